// Round 2
// 427.738 us; speedup vs baseline: 1.2392x; 1.2392x over previous
//
#include <hip/hip_runtime.h>

#define BB 4096
#define SS 128
#define NB 16
#define NT 256

typedef __attribute__((ext_vector_type(8))) short short8;
typedef __attribute__((ext_vector_type(4))) float f32x4;
typedef unsigned short ushort_t;
typedef unsigned int uint_t;

#define SX_STR   72
#define SH1_STR  264
#define SEMB_STR 136
#define SH_STR   72
#define ENC_LDS_USHORTS (32 * SH1_STR + 32 * SEMB_STR)   // 12800 -> 25.6 KB

__device__ __forceinline__ ushort_t f2bf(float f) {
    union { float f; unsigned u; } x; x.f = f;
    unsigned r = x.u + 0x7FFFu + ((x.u >> 16) & 1u);
    return (ushort_t)(r >> 16);
}
__device__ __forceinline__ uint_t pack2(float a, float b) {
    return (uint_t)f2bf(a) | ((uint_t)f2bf(b) << 16);
}
__device__ __forceinline__ float bflo(uint_t u) {
    union { unsigned u; float f; } x; x.u = u << 16; return x.f;
}
__device__ __forceinline__ float bfhi(uint_t u) {
    union { unsigned u; float f; } x; x.u = u & 0xFFFF0000u; return x.f;
}
__device__ __forceinline__ float bf2f(ushort_t h) {
    union { unsigned u; float f; } x; x.u = ((unsigned)h) << 16; return x.f;
}
__device__ __forceinline__ float fsig(float x) {
    return __builtin_amdgcn_rcpf(1.f + __expf(-x));
}
__device__ __forceinline__ float ftanh(float x) {
    return 1.f - 2.f * __builtin_amdgcn_rcpf(__expf(2.f * x) + 1.f);
}
// workgroup barrier WITHOUT vmcnt drain (LDS ordering only)
__device__ __forceinline__ void barrier_lgkm() {
    asm volatile("s_waitcnt lgkmcnt(0)\n\ts_barrier" ::: "memory");
}

union FragU { short8 v; ushort_t u[8]; };

// ============================================================================
// Prep: bf16 B-fragment images for W1/W2/Wih/Whh.
// ============================================================================
__global__ void podcritic_prep(const float* __restrict__ W1, const float* __restrict__ W2,
                               const float* __restrict__ Wih, const float* __restrict__ Whh,
                               short8* __restrict__ img)
{
    const int W = blockIdx.x * 4 + (threadIdx.x >> 6);   // 0..191
    const int l = threadIdx.x & 63;
    const int q = l >> 4, m = l & 15;
    FragU u;
    #pragma unroll
    for (int j = 0; j < 8; ++j) {
        float v;
        if (W < 32)       { int nt = W >> 1,        kk = W & 1;        int k = kk*32 + q*8 + j;
                            v = (k < 47) ? W1[k*256 + nt*16 + m] : 0.f; }
        else if (W < 96)  { int f = W - 32, nt = f >> 3, kk = f & 7;   int k = kk*32 + q*8 + j;
                            v = W2[k*128 + nt*16 + m]; }
        else if (W < 160) { int f = W - 96, nt = f >> 2, kk = f & 3;   int k = kk*32 + q*8 + j;
                            v = Wih[k*256 + nt*16 + m]; }
        else              { int f = W - 160, nt = f >> 1, kk = f & 1;  int k = kk*32 + q*8 + j;
                            v = Whh[k*256 + nt*16 + m]; }
        u.u[j] = f2bf(v);
    }
    img[W * 64 + l] = u.v;
}

// ============================================================================
// Encoder block: M=32 rows (2 steps x 16 batch), 3 lgkm barriers.
// Branchless gather; biases folded into accumulator init; per-phase
// fragment loads (compiler sinks them; keeps VGPR ~52).
// ============================================================================
__device__ __forceinline__ void enc_block(
    ushort_t* smem,
    const float* __restrict__ self_obs, const float* __restrict__ tm_obs,
    const float* __restrict__ en_obs,   const float* __restrict__ cp_obs,
    const float* __restrict__ b1, const float* __restrict__ b2,
    const float* __restrict__ bih, const float* __restrict__ bhh,
    const short8* __restrict__ img, uint_t* __restrict__ wx, int c0, int e)
{
    ushort_t* sh1 = smem;                     // 32*SH1_STR
    ushort_t* sxe = smem + 32 * SH1_STR;      // 32*SEMB_STR (x then emb)

    const int t = threadIdx.x;
    const int w = t >> 6, l = t & 63, q = l >> 4, m = l & 15;
    const int bg = e & 255, b0 = bg * NB;
    const int ytile = e >> 8;
    const int sbase = c0 + ytile * 2;

    // ---- branchless gather: resolve (ptr,stride,scale) once per lane ----
    {
        const int col = t & 63, rw0 = t >> 6;
        const float* p; int stride, soff; float scale;
        if (col < 15)      { p = self_obs + col;      stride = 15; soff = 0;  scale = 0.5f; }
        else if (col < 28) { p = tm_obs + (col - 15); stride = 13; soff = 0;  scale = 0.5f; }
        else if (col < 41) { p = en_obs + (col - 28); stride = 26; soff = 13; scale = 0.5f; }
        else if (col < 47) { p = cp_obs + (col - 41); stride = 6;  soff = 0;  scale = 0.5f; }
        else               { p = self_obs;            stride = 0;  soff = 0;  scale = 0.f; }
        #pragma unroll
        for (int jj = 0; jj < 8; ++jj) {
            int rr = 4 * jj + rw0;
            int mt = rr >> 4, r = rr & 15;
            int bs = (b0 + r) * SS + sbase + mt;
            int o = bs * stride;
            float v = scale * (p[o] + p[o + soff]);
            sxe[rr * SX_STR + col] = f2bf(v);
        }
    }
    float bias1[4], bias2[2], bgf[4];
    #pragma unroll
    for (int i = 0; i < 4; ++i) bias1[i] = b1[w * 64 + i * 16 + m];
    #pragma unroll
    for (int i = 0; i < 2; ++i) bias2[i] = b2[32 * w + 16 * i + m];
    #pragma unroll
    for (int i = 0; i < 4; ++i) { int n = (w + 4 * i) * 16 + m; bgf[i] = bih[n] + bhh[n]; }
    barrier_lgkm();

    // ---- phase 1: H1 = relu(x @ W1 + b1), M=32; bias in acc init ----
    {
        short8 w1f[4][2];
        #pragma unroll
        for (int i = 0; i < 4; ++i)
            #pragma unroll
            for (int kk = 0; kk < 2; ++kk)
                w1f[i][kk] = img[(((4 * w + i) * 2) + kk) * 64 + l];
        f32x4 c1[2][4];
        #pragma unroll
        for (int mt = 0; mt < 2; ++mt)
            #pragma unroll
            for (int i = 0; i < 4; ++i)
                c1[mt][i] = (f32x4){bias1[i], bias1[i], bias1[i], bias1[i]};
        #pragma unroll
        for (int kk = 0; kk < 2; ++kk) {
            #pragma unroll
            for (int mt = 0; mt < 2; ++mt) {
                short8 a = *(const short8*)&sxe[(mt * 16 + m) * SX_STR + kk * 32 + q * 8];
                #pragma unroll
                for (int i = 0; i < 4; ++i)
                    c1[mt][i] = __builtin_amdgcn_mfma_f32_16x16x32_bf16(a, w1f[i][kk], c1[mt][i], 0, 0, 0);
            }
        }
        #pragma unroll
        for (int mt = 0; mt < 2; ++mt)
            #pragma unroll
            for (int i = 0; i < 4; ++i) {
                int col = w * 64 + i * 16 + m;
                #pragma unroll
                for (int r = 0; r < 4; ++r)
                    sh1[(mt * 16 + q * 4 + r) * SH1_STR + col] = f2bf(fmaxf(c1[mt][i][r], 0.f));
            }
    }
    barrier_lgkm();

    // ---- phase 2: EMB = relu(H1 @ W2 + b2); bias in acc init ----
    {
        short8 w2f[2][8];
        #pragma unroll
        for (int i = 0; i < 2; ++i)
            #pragma unroll
            for (int kk = 0; kk < 8; ++kk)
                w2f[i][kk] = img[(32 + ((2 * w + i) * 8) + kk) * 64 + l];
        f32x4 c2[2][2];
        #pragma unroll
        for (int mt = 0; mt < 2; ++mt)
            #pragma unroll
            for (int i = 0; i < 2; ++i)
                c2[mt][i] = (f32x4){bias2[i], bias2[i], bias2[i], bias2[i]};
        #pragma unroll
        for (int kk = 0; kk < 8; ++kk) {
            #pragma unroll
            for (int mt = 0; mt < 2; ++mt) {
                short8 a = *(const short8*)&sh1[(mt * 16 + m) * SH1_STR + kk * 32 + q * 8];
                #pragma unroll
                for (int i = 0; i < 2; ++i)
                    c2[mt][i] = __builtin_amdgcn_mfma_f32_16x16x32_bf16(a, w2f[i][kk], c2[mt][i], 0, 0, 0);
            }
        }
        #pragma unroll
        for (int mt = 0; mt < 2; ++mt)
            #pragma unroll
            for (int i = 0; i < 2; ++i) {
                int col = 32 * w + 16 * i + m;
                #pragma unroll
                for (int r = 0; r < 4; ++r)
                    sxe[(mt * 16 + q * 4 + r) * SEMB_STR + col] = f2bf(fmaxf(c2[mt][i][r], 0.f));
            }
    }
    barrier_lgkm();

    // ---- phase 3: wx = emb @ Wih + (bih+bhh), swizzled store ----
    {
        short8 wihf[4][4];
        #pragma unroll
        for (int i = 0; i < 4; ++i)
            #pragma unroll
            for (int kk = 0; kk < 4; ++kk)
                wihf[i][kk] = img[(96 + ((w + 4 * i) * 4) + kk) * 64 + l];
        #pragma unroll
        for (int mt = 0; mt < 2; ++mt) {
            f32x4 g[4];
            #pragma unroll
            for (int i = 0; i < 4; ++i) g[i] = (f32x4){bgf[i], bgf[i], bgf[i], bgf[i]};
            #pragma unroll
            for (int kk = 0; kk < 4; ++kk) {
                short8 a = *(const short8*)&sxe[(mt * 16 + m) * SEMB_STR + kk * 32 + q * 8];
                #pragma unroll
                for (int i = 0; i < 4; ++i)
                    g[i] = __builtin_amdgcn_mfma_f32_16x16x32_bf16(a, wihf[i][kk], g[i], 0, 0, 0);
            }
            int slc = ytile * 2 + mt;
            uint_t* dst = wx + (size_t)(slc * 256 + bg) * 2048 + l * 2;
            #pragma unroll
            for (int i = 0; i < 4; ++i) {
                uint2 vv;
                vv.x = pack2(g[i][0], g[i][1]);
                vv.y = pack2(g[i][2], g[i][3]);
                *(uint2*)(dst + (w + 4 * i) * 128) = vv;
            }
        }
    }
}

// ============================================================================
// Recurrence block: 4 waves / 16 batch rows, 1 lgkm barrier/step,
// 2-deep wx prefetch, runtime chunk length with compile-time parity.
// ============================================================================
__device__ __forceinline__ void rec_block(
    ushort_t* smem,
    const short8* __restrict__ whhimg, const uint_t* __restrict__ wx,
    ushort_t* __restrict__ hws, float* __restrict__ cws,
    ushort_t* __restrict__ hseq, float* __restrict__ out,
    int first, int last, int csr)
{
    const int t = threadIdx.x;
    const int w = t >> 6, l = t & 63, q = l >> 4, m = l & 15;
    const int bg = blockIdx.x, b0 = bg * NB;

    short8 whhf[4][2];
    #pragma unroll
    for (int a = 0; a < 4; ++a)
        #pragma unroll
        for (int kk = 0; kk < 2; ++kk)
            whhf[a][kk] = whhimg[(((w + 4 * a) * 2) + kk) * 64 + l];

    float creg[4], hlast[4] = {0.f, 0.f, 0.f, 0.f};
    if (first) {
        #pragma unroll
        for (int r = 0; r < 4; ++r) creg[r] = 0.f;
        int idx4 = t * 4, row = idx4 >> 6, col = idx4 & 63;
        uint2 z; z.x = 0u; z.y = 0u;
        *(uint2*)&smem[row * SH_STR + col] = z;
    } else {
        int idx4 = t * 4, row = idx4 >> 6, col = idx4 & 63;
        uint2 hv2 = *(const uint2*)((const uint_t*)(hws + (size_t)bg * 1024 + idx4));
        *(uint2*)&smem[row * SH_STR + col] = hv2;
        float4 cv = *(const float4*)(cws + ((size_t)bg * 256 + t) * 4);
        creg[0] = cv.x; creg[1] = cv.y; creg[2] = cv.z; creg[3] = cv.w;
    }

    uint2 upf[2][4];
    {
        const uint_t* p0 = wx + (size_t)(0 * 256 + bg) * 2048 + l * 2;
        const uint_t* p1 = wx + (size_t)(1 * 256 + bg) * 2048 + l * 2;
        #pragma unroll
        for (int a = 0; a < 4; ++a) {
            upf[0][a] = *(const uint2*)(p0 + (w + 4 * a) * 128);
            upf[1][a] = *(const uint2*)(p1 + (w + 4 * a) * 128);
        }
    }
    ushort_t* hsp = hseq + (size_t)(b0 + q * 4) * 64 + 16 * w + m;
    const size_t hstep = (size_t)BB * 64;

    barrier_lgkm();

    #define REC_STEP(PAR, SLV)                                                          \
    do {                                                                                \
        const int sl_ = (SLV);                                                          \
        ushort_t* shc = smem + (PAR) * (NB * SH_STR);                                   \
        ushort_t* shn = smem + (1 - (PAR)) * (NB * SH_STR);                             \
        short8 af0 = *(const short8*)&shc[m * SH_STR + q * 8];                          \
        short8 af1 = *(const short8*)&shc[m * SH_STR + 32 + q * 8];                     \
        f32x4 g[4];                                                                     \
        _Pragma("unroll")                                                               \
        for (int a = 0; a < 4; ++a) {                                                   \
            g[a][0] = bflo(upf[PAR][a].x); g[a][1] = bfhi(upf[PAR][a].x);               \
            g[a][2] = bflo(upf[PAR][a].y); g[a][3] = bfhi(upf[PAR][a].y);               \
        }                                                                               \
        {                                                                               \
            int snext = (sl_ + 2 < csr) ? (sl_ + 2) : sl_;                              \
            const uint_t* pn = wx + (size_t)(snext * 256 + bg) * 2048 + l * 2;          \
            _Pragma("unroll")                                                           \
            for (int a = 0; a < 4; ++a)                                                 \
                upf[PAR][a] = *(const uint2*)(pn + (w + 4 * a) * 128);                  \
        }                                                                               \
        _Pragma("unroll")                                                               \
        for (int a = 0; a < 4; ++a) {                                                   \
            g[a] = __builtin_amdgcn_mfma_f32_16x16x32_bf16(af0, whhf[a][0], g[a], 0, 0, 0); \
            g[a] = __builtin_amdgcn_mfma_f32_16x16x32_bf16(af1, whhf[a][1], g[a], 0, 0, 0); \
        }                                                                               \
        _Pragma("unroll")                                                               \
        for (int r = 0; r < 4; ++r) {                                                   \
            float gi = fsig(g[0][r]);                                                   \
            float gf = fsig(g[1][r]);                                                   \
            float gg = ftanh(g[2][r]);                                                  \
            float go = fsig(g[3][r]);                                                   \
            float c  = gf * creg[r] + gi * gg;                                          \
            creg[r] = c;                                                                \
            float h = go * ftanh(c);                                                    \
            hlast[r] = h;                                                               \
            ushort_t hb = f2bf(h);                                                      \
            shn[(q * 4 + r) * SH_STR + 16 * w + m] = hb;                                \
            hsp[(size_t)sl_ * hstep + r * 64] = hb;                                     \
        }                                                                               \
        barrier_lgkm();                                                                 \
    } while (0)

    for (int sl = 0; sl < csr; sl += 2) {
        REC_STEP(0, sl);
        REC_STEP(1, sl + 1);
    }
    #undef REC_STEP

    if (!last) {
        const int jcol = 16 * w + m;
        #pragma unroll
        for (int r = 0; r < 4; ++r)
            hws[(size_t)bg * 1024 + (q * 4 + r) * 64 + jcol] = f2bf(hlast[r]);
        float4 cv; cv.x = creg[0]; cv.y = creg[1]; cv.z = creg[2]; cv.w = creg[3];
        *(float4*)(cws + ((size_t)bg * 256 + t) * 4) = cv;
    } else {
        const int jcol = 16 * w + m;
        #pragma unroll
        for (int r = 0; r < 4; ++r) {
            int row = b0 + q * 4 + r;
            out[BB * SS + (size_t)row * 64 + jcol]           = hlast[r];
            out[BB * SS + BB * 64 + (size_t)row * 64 + jcol] = creg[r];
        }
    }
}

// ============================================================================
// Deferred value head: 256 rows per block, 1 row per thread; Wv/bv uniform
// (scalarized by compiler). Wave reads 64 contiguous 128B rows -> coalesced.
// ============================================================================
__device__ __forceinline__ void val_block(
    const ushort_t* __restrict__ hseq, const float* __restrict__ Wv,
    const float* __restrict__ bv, float* __restrict__ out, int c0, int vb)
{
    const int t = threadIdx.x;
    const int row = vb * 256 + t;
    const ushort_t* hp = hseq + (size_t)row * 64;
    float pv = bv[0];
    #pragma unroll
    for (int k = 0; k < 8; ++k) {
        uint4 hv = *(const uint4*)(hp + k * 8);
        float4 w0 = *(const float4*)(Wv + k * 8);
        float4 w1 = *(const float4*)(Wv + k * 8 + 4);
        pv += bflo(hv.x) * w0.x + bfhi(hv.x) * w0.y
            + bflo(hv.y) * w0.z + bfhi(hv.y) * w0.w
            + bflo(hv.z) * w1.x + bfhi(hv.z) * w1.y
            + bflo(hv.w) * w1.z + bfhi(hv.w) * w1.w;
    }
    int sl = row >> 12, b = row & 4095;
    out[(size_t)b * SS + c0 + sl] = pv;
}

// ============================================================================
// Combined pipeline dispatch: [0,nrec) rec(c) | [nrec,nrec+nenc) enc(c+1) |
// rest val(c-1). No intra-dispatch dependencies (wx + hseq double-buffered).
// ============================================================================
__global__ __launch_bounds__(NT, 4)
void podcritic_step(const float* __restrict__ self_obs, const float* __restrict__ tm_obs,
                    const float* __restrict__ en_obs,   const float* __restrict__ cp_obs,
                    const float* __restrict__ b1, const float* __restrict__ b2,
                    const float* __restrict__ bih, const float* __restrict__ bhh,
                    const short8* __restrict__ img,
                    uint_t* __restrict__ wx_enc, const uint_t* __restrict__ wx_rec,
                    ushort_t* __restrict__ hws, float* __restrict__ cws,
                    ushort_t* __restrict__ hseq_rec, const ushort_t* __restrict__ hseq_val,
                    const float* __restrict__ Wv, const float* __restrict__ bv,
                    float* __restrict__ out,
                    int enc_c0, int val_c0, int nrec, int nenc, int first, int last, int csr)
{
    __shared__ __align__(16) ushort_t smem[ENC_LDS_USHORTS];
    const int bid = blockIdx.x;
    if (bid < nrec) {
        rec_block(smem, img + 160 * 64, wx_rec, hws, cws, hseq_rec, out, first, last, csr);
    } else if (bid < nrec + nenc) {
        enc_block(smem, self_obs, tm_obs, en_obs, cp_obs, b1, b2, bih, bhh,
                  img, wx_enc, enc_c0, bid - nrec);
    } else {
        val_block(hseq_val, Wv, bv, out, val_c0, bid - nrec - nenc);
    }
}

// ============================================================================
// Fallback: fused kernel (only if ws too small) — round-2 structure.
// ============================================================================
__global__ __launch_bounds__(NT, 1)
void podcritic_mfma(const float* __restrict__ self_obs,
                    const float* __restrict__ tm_obs,
                    const float* __restrict__ en_obs,
                    const float* __restrict__ cp_obs,
                    const float* __restrict__ W1, const float* __restrict__ b1,
                    const float* __restrict__ W2, const float* __restrict__ b2,
                    const float* __restrict__ Wih, const float* __restrict__ bih,
                    const float* __restrict__ Whh, const float* __restrict__ bhh,
                    const float* __restrict__ Wv, const float* __restrict__ bv,
                    float* __restrict__ out)
{
    __shared__ __align__(16) ushort_t sx[2][NB * SX_STR];
    __shared__ __align__(16) ushort_t sh1[NB * SH1_STR];
    __shared__ __align__(16) ushort_t semb[NB * SEMB_STR];
    __shared__ __align__(16) ushort_t sh[NB * SH_STR];
    __shared__ float sWv[64];

    const int t  = threadIdx.x;
    const int w  = t >> 6;
    const int l  = t & 63;
    const int q  = l >> 4;
    const int m  = l & 15;
    const int b0 = blockIdx.x * NB;

    short8 w1f[4][2];
    short8 w2f[2][8];
    short8 wihf[4][4];
    short8 whhf[4][2];
    float bias1[4], bias2[2], bg[4];

    #pragma unroll
    for (int i = 0; i < 4; ++i) {
        int n = w * 64 + i * 16 + m;
        bias1[i] = b1[n];
        #pragma unroll
        for (int kk = 0; kk < 2; ++kk) {
            FragU u;
            #pragma unroll
            for (int j = 0; j < 8; ++j) {
                int k = kk * 32 + q * 8 + j;
                u.u[j] = f2bf(k < 47 ? W1[k * 256 + n] : 0.f);
            }
            w1f[i][kk] = u.v;
        }
    }
    #pragma unroll
    for (int i = 0; i < 2; ++i) {
        int n = 32 * w + i * 16 + m;
        bias2[i] = b2[n];
        #pragma unroll
        for (int kk = 0; kk < 8; ++kk) {
            FragU u;
            #pragma unroll
            for (int j = 0; j < 8; ++j) {
                int k = kk * 32 + q * 8 + j;
                u.u[j] = f2bf(W2[k * 128 + n]);
            }
            w2f[i][kk] = u.v;
        }
    }
    #pragma unroll
    for (int i = 0; i < 4; ++i) {
        int n = (w + 4 * i) * 16 + m;
        bg[i] = bih[n] + bhh[n];
        #pragma unroll
        for (int kk = 0; kk < 4; ++kk) {
            FragU u;
            #pragma unroll
            for (int j = 0; j < 8; ++j) {
                int k = kk * 32 + q * 8 + j;
                u.u[j] = f2bf(Wih[k * 256 + n]);
            }
            wihf[i][kk] = u.v;
        }
        #pragma unroll
        for (int kk = 0; kk < 2; ++kk) {
            FragU u;
            #pragma unroll
            for (int j = 0; j < 8; ++j) {
                int k = kk * 32 + q * 8 + j;
                u.u[j] = f2bf(Whh[k * 256 + n]);
            }
            whhf[i][kk] = u.v;
        }
    }
    const float bvv = bv[0];
    if (t < 64) sWv[t] = Wv[t];

    for (int idx = t; idx < NB * SH_STR; idx += NT) sh[idx] = 0;

    const int pcol = t & 63;
    const int prow = t >> 6;
    #pragma unroll
    for (int j = 0; j < 4; ++j) {
        int r  = 4 * j + prow;
        int bs = (b0 + r) * SS + 0;
        float v = 0.f;
        if (pcol < 15)      v = self_obs[bs * 15 + pcol];
        else if (pcol < 28) v = tm_obs[bs * 13 + (pcol - 15)];
        else if (pcol < 41) { int kk = pcol - 28;
                              v = 0.5f * (en_obs[(bs * 2) * 13 + kk] + en_obs[(bs * 2) * 13 + 13 + kk]); }
        else if (pcol < 47) v = cp_obs[bs * 6 + (pcol - 41)];
        sx[0][r * SX_STR + pcol] = f2bf(v);
    }
    __syncthreads();

    float creg[4] = {0.f, 0.f, 0.f, 0.f};
    float hreg[4] = {0.f, 0.f, 0.f, 0.f};
    int cur = 0;

    for (int s = 0; s < SS; ++s) {
        float pf[4];
        #pragma unroll
        for (int j = 0; j < 4; ++j) {
            float v = 0.f;
            if (s + 1 < SS) {
                int r  = 4 * j + prow;
                int bs = (b0 + r) * SS + (s + 1);
                if (pcol < 15)      v = self_obs[bs * 15 + pcol];
                else if (pcol < 28) v = tm_obs[bs * 13 + (pcol - 15)];
                else if (pcol < 41) { int kk = pcol - 28;
                                      v = 0.5f * (en_obs[(bs * 2) * 13 + kk] + en_obs[(bs * 2) * 13 + 13 + kk]); }
                else if (pcol < 47) v = cp_obs[bs * 6 + (pcol - 41)];
            }
            pf[j] = v;
        }

        {
            f32x4 c1[4] = {{0,0,0,0},{0,0,0,0},{0,0,0,0},{0,0,0,0}};
            #pragma unroll
            for (int kk = 0; kk < 2; ++kk) {
                short8 a = *(const short8*)&sx[cur][m * SX_STR + kk * 32 + q * 8];
                #pragma unroll
                for (int i = 0; i < 4; ++i)
                    c1[i] = __builtin_amdgcn_mfma_f32_16x16x32_bf16(a, w1f[i][kk], c1[i], 0, 0, 0);
            }
            #pragma unroll
            for (int i = 0; i < 4; ++i) {
                int col = w * 64 + i * 16 + m;
                #pragma unroll
                for (int r = 0; r < 4; ++r)
                    sh1[(q * 4 + r) * SH1_STR + col] = f2bf(fmaxf(c1[i][r] + bias1[i], 0.f));
            }
        }
        __syncthreads();

        {
            f32x4 c2[2] = {{0,0,0,0},{0,0,0,0}};
            #pragma unroll
            for (int kk = 0; kk < 8; ++kk) {
                short8 a = *(const short8*)&sh1[m * SH1_STR + kk * 32 + q * 8];
                #pragma unroll
                for (int i = 0; i < 2; ++i)
                    c2[i] = __builtin_amdgcn_mfma_f32_16x16x32_bf16(a, w2f[i][kk], c2[i], 0, 0, 0);
            }
            #pragma unroll
            for (int i = 0; i < 2; ++i) {
                int col = 32 * w + i * 16 + m;
                #pragma unroll
                for (int r = 0; r < 4; ++r)
                    semb[(q * 4 + r) * SEMB_STR + col] = f2bf(fmaxf(c2[i][r] + bias2[i], 0.f));
            }
        }
        __syncthreads();

        {
            f32x4 g[4];
            #pragma unroll
            for (int i = 0; i < 4; ++i) g[i] = (f32x4){bg[i], bg[i], bg[i], bg[i]};
            #pragma unroll
            for (int kk = 0; kk < 4; ++kk) {
                short8 a = *(const short8*)&semb[m * SEMB_STR + kk * 32 + q * 8];
                #pragma unroll
                for (int i = 0; i < 4; ++i)
                    g[i] = __builtin_amdgcn_mfma_f32_16x16x32_bf16(a, wihf[i][kk], g[i], 0, 0, 0);
            }
            #pragma unroll
            for (int kk = 0; kk < 2; ++kk) {
                short8 a = *(const short8*)&sh[m * SH_STR + kk * 32 + q * 8];
                #pragma unroll
                for (int i = 0; i < 4; ++i)
                    g[i] = __builtin_amdgcn_mfma_f32_16x16x32_bf16(a, whhf[i][kk], g[i], 0, 0, 0);
            }
            const int jcol = 16 * w + m;
            #pragma unroll
            for (int r = 0; r < 4; ++r) {
                float gi = fsig(g[0][r]);
                float gf = fsig(g[1][r]);
                float gg = ftanh(g[2][r]);
                float go = fsig(g[3][r]);
                float c  = gf * creg[r] + gi * gg;
                creg[r] = c;
                float h = go * ftanh(c);
                hreg[r] = h;
                sh[(q * 4 + r) * SH_STR + jcol] = f2bf(h);
            }
            #pragma unroll
            for (int j = 0; j < 4; ++j) {
                int r = 4 * j + prow;
                sx[cur ^ 1][r * SX_STR + pcol] = f2bf(pf[j]);
            }
        }
        __syncthreads();

        {
            int r = t >> 4, pp = t & 15;
            const ushort_t* hp = &sh[r * SH_STR + pp * 4];
            float pv = 0.f;
            #pragma unroll
            for (int j = 0; j < 4; ++j) pv += bf2f(hp[j]) * sWv[pp * 4 + j];
            pv += __shfl_xor(pv, 1, 16);
            pv += __shfl_xor(pv, 2, 16);
            pv += __shfl_xor(pv, 4, 16);
            pv += __shfl_xor(pv, 8, 16);
            if (pp == 0) out[(b0 + r) * SS + s] = pv + bvv;
        }
        cur ^= 1;
    }

    {
        const int jcol = 16 * w + m;
        #pragma unroll
        for (int r = 0; r < 4; ++r) {
            int row = b0 + q * 4 + r;
            out[BB * SS + row * 64 + jcol]           = hreg[r];
            out[BB * SS + BB * 64 + row * 64 + jcol] = creg[r];
        }
    }
}

extern "C" void kernel_launch(void* const* d_in, const int* in_sizes, int n_in,
                              void* d_out, int out_size, void* d_ws, size_t ws_size,
                              hipStream_t stream) {
    const float* self_obs = (const float*)d_in[0];
    const float* tm_obs   = (const float*)d_in[1];
    const float* en_obs   = (const float*)d_in[2];
    const float* cp_obs   = (const float*)d_in[3];
    const float* W1  = (const float*)d_in[4];
    const float* b1  = (const float*)d_in[5];
    const float* W2  = (const float*)d_in[6];
    const float* b2  = (const float*)d_in[7];
    const float* Wih = (const float*)d_in[8];
    const float* bih = (const float*)d_in[9];
    const float* Whh = (const float*)d_in[10];
    const float* bhh = (const float*)d_in[11];
    const float* Wv  = (const float*)d_in[12];
    const float* bv  = (const float*)d_in[13];
    float* out = (float*)d_out;

    const size_t h_bytes   = 256 * 1024 * 2;                // 524,288
    const size_t c_bytes   = 256 * 1024 * 4;                // 1,048,576
    const size_t img_bytes = 192 * 64 * 16;                 // 196,608

    // CS=16 only this round (HW-verified schedule); runtime-csr plumbing kept.
    const int CSr = 16, NCHr = 8;
    const size_t wx_chunk   = (size_t)CSr * 256 * 2048 * 4;
    const size_t hseq_chunk = (size_t)CSr * BB * 64 * 2;
    const size_t need = 2 * wx_chunk + h_bytes + c_bytes + img_bytes + 2 * hseq_chunk;

    if (ws_size >= need) {
        char* p = (char*)d_ws;
        uint_t*   wxb[2]   = { (uint_t*)p, (uint_t*)(p + wx_chunk) };
        ushort_t* hws      = (ushort_t*)(p + 2 * wx_chunk);
        float*    cws      = (float*)(p + 2 * wx_chunk + h_bytes);
        short8*   img      = (short8*)(p + 2 * wx_chunk + h_bytes + c_bytes);
        ushort_t* hseqb[2] = { (ushort_t*)(p + 2 * wx_chunk + h_bytes + c_bytes + img_bytes),
                               (ushort_t*)(p + 2 * wx_chunk + h_bytes + c_bytes + img_bytes + hseq_chunk) };

        const int nenc_full = 128 * CSr;        // 2048 enc blocks per chunk
        const int nval_full = CSr * BB / 256;   // 256 val blocks per chunk

        podcritic_prep<<<48, NT, 0, stream>>>(W1, W2, Wih, Whh, img);

        // head: enc chunk 0 alone
        podcritic_step<<<nenc_full, NT, 0, stream>>>(
            self_obs, tm_obs, en_obs, cp_obs, b1, b2, bih, bhh, img,
            wxb[0], wxb[0], hws, cws, hseqb[0], hseqb[0], Wv, bv, out,
            /*enc_c0=*/0, /*val_c0=*/0, /*nrec=*/0, /*nenc=*/nenc_full, 0, 0, CSr);

        for (int c = 0; c < NCHr; ++c) {
            int nenc = (c + 1 < NCHr) ? nenc_full : 0;
            int nval = (c > 0) ? nval_full : 0;
            int grid = 256 + nenc + nval;
            podcritic_step<<<grid, NT, 0, stream>>>(
                self_obs, tm_obs, en_obs, cp_obs, b1, b2, bih, bhh, img,
                wxb[(c + 1) & 1], wxb[c & 1], hws, cws,
                hseqb[c & 1], hseqb[(c > 0 ? (c - 1) : 0) & 1], Wv, bv, out,
                /*enc_c0=*/(c + 1) * CSr, /*val_c0=*/(c - 1) * CSr,
                /*nrec=*/256, nenc, (c == 0) ? 1 : 0, (c == NCHr - 1) ? 1 : 0, CSr);
        }
        // tail: val for last chunk
        podcritic_step<<<nval_full, NT, 0, stream>>>(
            self_obs, tm_obs, en_obs, cp_obs, b1, b2, bih, bhh, img,
            wxb[0], wxb[0], hws, cws, hseqb[0], hseqb[(NCHr - 1) & 1], Wv, bv, out,
            /*enc_c0=*/0, /*val_c0=*/(NCHr - 1) * CSr, /*nrec=*/0, /*nenc=*/0, 0, 0, CSr);
    } else {
        podcritic_mfma<<<BB / NB, NT, 0, stream>>>(
            self_obs, tm_obs, en_obs, cp_obs,
            W1, b1, W2, b2, Wih, bih, Whh, bhh, Wv, bv, out);
    }
}

// Round 3
// 393.570 us; speedup vs baseline: 1.3467x; 1.0868x over previous
//
#include <hip/hip_runtime.h>

#define BB 4096
#define SS 128
#define NB 16
#define NT 256

typedef __attribute__((ext_vector_type(8))) short short8;
typedef __attribute__((ext_vector_type(4))) float f32x4;
typedef unsigned short ushort_t;
typedef unsigned int uint_t;

#define SX_STR   72
#define SH1_STR  264
#define SEMB_STR 136
#define SH_STR   72
#define ENC_LDS_USHORTS (32 * SH1_STR + 32 * SEMB_STR)   // 12800 -> 25.6 KB

__device__ __forceinline__ ushort_t f2bf(float f) {
    union { float f; unsigned u; } x; x.f = f;
    unsigned r = x.u + 0x7FFFu + ((x.u >> 16) & 1u);
    return (ushort_t)(r >> 16);
}
__device__ __forceinline__ uint_t pack2(float a, float b) {
    return (uint_t)f2bf(a) | ((uint_t)f2bf(b) << 16);
}
__device__ __forceinline__ float bflo(uint_t u) {
    union { unsigned u; float f; } x; x.u = u << 16; return x.f;
}
__device__ __forceinline__ float bfhi(uint_t u) {
    union { unsigned u; float f; } x; x.u = u & 0xFFFF0000u; return x.f;
}
__device__ __forceinline__ float bf2f(ushort_t h) {
    union { unsigned u; float f; } x; x.u = ((unsigned)h) << 16; return x.f;
}
__device__ __forceinline__ float fsig(float x) {
    return __builtin_amdgcn_rcpf(1.f + __expf(-x));
}
__device__ __forceinline__ float ftanh(float x) {
    return 1.f - 2.f * __builtin_amdgcn_rcpf(__expf(2.f * x) + 1.f);
}
// workgroup barrier WITHOUT vmcnt drain (LDS ordering only)
__device__ __forceinline__ void barrier_lgkm() {
    asm volatile("s_waitcnt lgkmcnt(0)\n\ts_barrier" ::: "memory");
}

union FragU { short8 v; ushort_t u[8]; };

// ============================================================================
// Prep: bf16 B-fragment images for W1/W2/Wih/Whh.
// ============================================================================
__global__ void podcritic_prep(const float* __restrict__ W1, const float* __restrict__ W2,
                               const float* __restrict__ Wih, const float* __restrict__ Whh,
                               short8* __restrict__ img)
{
    const int W = blockIdx.x * 4 + (threadIdx.x >> 6);   // 0..191
    const int l = threadIdx.x & 63;
    const int q = l >> 4, m = l & 15;
    FragU u;
    #pragma unroll
    for (int j = 0; j < 8; ++j) {
        float v;
        if (W < 32)       { int nt = W >> 1,        kk = W & 1;        int k = kk*32 + q*8 + j;
                            v = (k < 47) ? W1[k*256 + nt*16 + m] : 0.f; }
        else if (W < 96)  { int f = W - 32, nt = f >> 3, kk = f & 7;   int k = kk*32 + q*8 + j;
                            v = W2[k*128 + nt*16 + m]; }
        else if (W < 160) { int f = W - 96, nt = f >> 2, kk = f & 3;   int k = kk*32 + q*8 + j;
                            v = Wih[k*256 + nt*16 + m]; }
        else              { int f = W - 160, nt = f >> 1, kk = f & 1;  int k = kk*32 + q*8 + j;
                            v = Whh[k*256 + nt*16 + m]; }
        u.u[j] = f2bf(v);
    }
    img[W * 64 + l] = u.v;
}

// ============================================================================
// Encoder block: M=32 rows (2 steps x 16 batch), 3 lgkm barriers.
// Branchless gather; biases folded into accumulator init; per-phase
// fragment loads (compiler sinks them; keeps VGPR ~52).
// ============================================================================
__device__ __forceinline__ void enc_block(
    ushort_t* smem,
    const float* __restrict__ self_obs, const float* __restrict__ tm_obs,
    const float* __restrict__ en_obs,   const float* __restrict__ cp_obs,
    const float* __restrict__ b1, const float* __restrict__ b2,
    const float* __restrict__ bih, const float* __restrict__ bhh,
    const short8* __restrict__ img, uint_t* __restrict__ wx, int c0, int e)
{
    ushort_t* sh1 = smem;                     // 32*SH1_STR
    ushort_t* sxe = smem + 32 * SH1_STR;      // 32*SEMB_STR (x then emb)

    const int t = threadIdx.x;
    const int w = t >> 6, l = t & 63, q = l >> 4, m = l & 15;
    const int bg = e & 255, b0 = bg * NB;
    const int ytile = e >> 8;
    const int sbase = c0 + ytile * 2;

    // ---- branchless gather: resolve (ptr,stride,scale) once per lane ----
    {
        const int col = t & 63, rw0 = t >> 6;
        const float* p; int stride, soff; float scale;
        if (col < 15)      { p = self_obs + col;      stride = 15; soff = 0;  scale = 0.5f; }
        else if (col < 28) { p = tm_obs + (col - 15); stride = 13; soff = 0;  scale = 0.5f; }
        else if (col < 41) { p = en_obs + (col - 28); stride = 26; soff = 13; scale = 0.5f; }
        else if (col < 47) { p = cp_obs + (col - 41); stride = 6;  soff = 0;  scale = 0.5f; }
        else               { p = self_obs;            stride = 0;  soff = 0;  scale = 0.f; }
        #pragma unroll
        for (int jj = 0; jj < 8; ++jj) {
            int rr = 4 * jj + rw0;
            int mt = rr >> 4, r = rr & 15;
            int bs = (b0 + r) * SS + sbase + mt;
            int o = bs * stride;
            float v = scale * (p[o] + p[o + soff]);
            sxe[rr * SX_STR + col] = f2bf(v);
        }
    }
    float bias1[4], bias2[2], bgf[4];
    #pragma unroll
    for (int i = 0; i < 4; ++i) bias1[i] = b1[w * 64 + i * 16 + m];
    #pragma unroll
    for (int i = 0; i < 2; ++i) bias2[i] = b2[32 * w + 16 * i + m];
    #pragma unroll
    for (int i = 0; i < 4; ++i) { int n = (w + 4 * i) * 16 + m; bgf[i] = bih[n] + bhh[n]; }
    barrier_lgkm();

    // ---- phase 1: H1 = relu(x @ W1 + b1), M=32; bias in acc init ----
    {
        short8 w1f[4][2];
        #pragma unroll
        for (int i = 0; i < 4; ++i)
            #pragma unroll
            for (int kk = 0; kk < 2; ++kk)
                w1f[i][kk] = img[(((4 * w + i) * 2) + kk) * 64 + l];
        f32x4 c1[2][4];
        #pragma unroll
        for (int mt = 0; mt < 2; ++mt)
            #pragma unroll
            for (int i = 0; i < 4; ++i)
                c1[mt][i] = (f32x4){bias1[i], bias1[i], bias1[i], bias1[i]};
        #pragma unroll
        for (int kk = 0; kk < 2; ++kk) {
            #pragma unroll
            for (int mt = 0; mt < 2; ++mt) {
                short8 a = *(const short8*)&sxe[(mt * 16 + m) * SX_STR + kk * 32 + q * 8];
                #pragma unroll
                for (int i = 0; i < 4; ++i)
                    c1[mt][i] = __builtin_amdgcn_mfma_f32_16x16x32_bf16(a, w1f[i][kk], c1[mt][i], 0, 0, 0);
            }
        }
        #pragma unroll
        for (int mt = 0; mt < 2; ++mt)
            #pragma unroll
            for (int i = 0; i < 4; ++i) {
                int col = w * 64 + i * 16 + m;
                #pragma unroll
                for (int r = 0; r < 4; ++r)
                    sh1[(mt * 16 + q * 4 + r) * SH1_STR + col] = f2bf(fmaxf(c1[mt][i][r], 0.f));
            }
    }
    barrier_lgkm();

    // ---- phase 2: EMB = relu(H1 @ W2 + b2); bias in acc init ----
    {
        short8 w2f[2][8];
        #pragma unroll
        for (int i = 0; i < 2; ++i)
            #pragma unroll
            for (int kk = 0; kk < 8; ++kk)
                w2f[i][kk] = img[(32 + ((2 * w + i) * 8) + kk) * 64 + l];
        f32x4 c2[2][2];
        #pragma unroll
        for (int mt = 0; mt < 2; ++mt)
            #pragma unroll
            for (int i = 0; i < 2; ++i)
                c2[mt][i] = (f32x4){bias2[i], bias2[i], bias2[i], bias2[i]};
        #pragma unroll
        for (int kk = 0; kk < 8; ++kk) {
            #pragma unroll
            for (int mt = 0; mt < 2; ++mt) {
                short8 a = *(const short8*)&sh1[(mt * 16 + m) * SH1_STR + kk * 32 + q * 8];
                #pragma unroll
                for (int i = 0; i < 2; ++i)
                    c2[mt][i] = __builtin_amdgcn_mfma_f32_16x16x32_bf16(a, w2f[i][kk], c2[mt][i], 0, 0, 0);
            }
        }
        #pragma unroll
        for (int mt = 0; mt < 2; ++mt)
            #pragma unroll
            for (int i = 0; i < 2; ++i) {
                int col = 32 * w + 16 * i + m;
                #pragma unroll
                for (int r = 0; r < 4; ++r)
                    sxe[(mt * 16 + q * 4 + r) * SEMB_STR + col] = f2bf(fmaxf(c2[mt][i][r], 0.f));
            }
    }
    barrier_lgkm();

    // ---- phase 3: wx = emb @ Wih + (bih+bhh), swizzled store ----
    {
        short8 wihf[4][4];
        #pragma unroll
        for (int i = 0; i < 4; ++i)
            #pragma unroll
            for (int kk = 0; kk < 4; ++kk)
                wihf[i][kk] = img[(96 + ((w + 4 * i) * 4) + kk) * 64 + l];
        #pragma unroll
        for (int mt = 0; mt < 2; ++mt) {
            f32x4 g[4];
            #pragma unroll
            for (int i = 0; i < 4; ++i) g[i] = (f32x4){bgf[i], bgf[i], bgf[i], bgf[i]};
            #pragma unroll
            for (int kk = 0; kk < 4; ++kk) {
                short8 a = *(const short8*)&sxe[(mt * 16 + m) * SEMB_STR + kk * 32 + q * 8];
                #pragma unroll
                for (int i = 0; i < 4; ++i)
                    g[i] = __builtin_amdgcn_mfma_f32_16x16x32_bf16(a, wihf[i][kk], g[i], 0, 0, 0);
            }
            int slc = ytile * 2 + mt;
            uint_t* dst = wx + (size_t)(slc * 256 + bg) * 2048 + l * 2;
            #pragma unroll
            for (int i = 0; i < 4; ++i) {
                uint2 vv;
                vv.x = pack2(g[i][0], g[i][1]);
                vv.y = pack2(g[i][2], g[i][3]);
                *(uint2*)(dst + (w + 4 * i) * 128) = vv;
            }
        }
    }
}

// ============================================================================
// Recurrence block with FUSED value head: 4 waves / 16 batch rows,
// 1 lgkm barrier/step, 2-deep wx prefetch. After each step's barrier, the
// value dot-product reads this step's h from LDS (shn) — off the recurrence
// critical path (next step writes the OTHER h buffer; the following step's
// lgkmcnt(0) barrier retires these reads before any overwrite).
// ============================================================================
__device__ __forceinline__ void rec_block(
    ushort_t* smem,
    const short8* __restrict__ whhimg, const uint_t* __restrict__ wx,
    ushort_t* __restrict__ hws, float* __restrict__ cws,
    const float* __restrict__ Wv, const float* __restrict__ bv,
    float* __restrict__ out, int rc0, int first, int last, int csr)
{
    const int t = threadIdx.x;
    const int w = t >> 6, l = t & 63, q = l >> 4, m = l & 15;
    const int bg = blockIdx.x, b0 = bg * NB;
    const int vr = t >> 4, vp = t & 15;           // value-head row / col-group

    short8 whhf[4][2];
    #pragma unroll
    for (int a = 0; a < 4; ++a)
        #pragma unroll
        for (int kk = 0; kk < 2; ++kk)
            whhf[a][kk] = whhimg[(((w + 4 * a) * 2) + kk) * 64 + l];

    const float4 wv = *(const float4*)(Wv + vp * 4);
    const float bvv = bv[0];

    float creg[4], hlast[4] = {0.f, 0.f, 0.f, 0.f};
    if (first) {
        #pragma unroll
        for (int r = 0; r < 4; ++r) creg[r] = 0.f;
        int idx4 = t * 4, row = idx4 >> 6, col = idx4 & 63;
        uint2 z; z.x = 0u; z.y = 0u;
        *(uint2*)&smem[row * SH_STR + col] = z;
    } else {
        int idx4 = t * 4, row = idx4 >> 6, col = idx4 & 63;
        uint2 hv2 = *(const uint2*)((const uint_t*)(hws + (size_t)bg * 1024 + idx4));
        *(uint2*)&smem[row * SH_STR + col] = hv2;
        float4 cv = *(const float4*)(cws + ((size_t)bg * 256 + t) * 4);
        creg[0] = cv.x; creg[1] = cv.y; creg[2] = cv.z; creg[3] = cv.w;
    }

    uint2 upf[2][4];
    {
        const uint_t* p0 = wx + (size_t)(0 * 256 + bg) * 2048 + l * 2;
        const uint_t* p1 = wx + (size_t)(1 * 256 + bg) * 2048 + l * 2;
        #pragma unroll
        for (int a = 0; a < 4; ++a) {
            upf[0][a] = *(const uint2*)(p0 + (w + 4 * a) * 128);
            upf[1][a] = *(const uint2*)(p1 + (w + 4 * a) * 128);
        }
    }

    barrier_lgkm();

    #define REC_STEP(PAR, SLV)                                                          \
    do {                                                                                \
        const int sl_ = (SLV);                                                          \
        ushort_t* shc = smem + (PAR) * (NB * SH_STR);                                   \
        ushort_t* shn = smem + (1 - (PAR)) * (NB * SH_STR);                             \
        short8 af0 = *(const short8*)&shc[m * SH_STR + q * 8];                          \
        short8 af1 = *(const short8*)&shc[m * SH_STR + 32 + q * 8];                     \
        f32x4 g[4];                                                                     \
        _Pragma("unroll")                                                               \
        for (int a = 0; a < 4; ++a) {                                                   \
            g[a][0] = bflo(upf[PAR][a].x); g[a][1] = bfhi(upf[PAR][a].x);               \
            g[a][2] = bflo(upf[PAR][a].y); g[a][3] = bfhi(upf[PAR][a].y);               \
        }                                                                               \
        {                                                                               \
            int snext = (sl_ + 2 < csr) ? (sl_ + 2) : sl_;                              \
            const uint_t* pn = wx + (size_t)(snext * 256 + bg) * 2048 + l * 2;          \
            _Pragma("unroll")                                                           \
            for (int a = 0; a < 4; ++a)                                                 \
                upf[PAR][a] = *(const uint2*)(pn + (w + 4 * a) * 128);                  \
        }                                                                               \
        _Pragma("unroll")                                                               \
        for (int a = 0; a < 4; ++a) {                                                   \
            g[a] = __builtin_amdgcn_mfma_f32_16x16x32_bf16(af0, whhf[a][0], g[a], 0, 0, 0); \
            g[a] = __builtin_amdgcn_mfma_f32_16x16x32_bf16(af1, whhf[a][1], g[a], 0, 0, 0); \
        }                                                                               \
        _Pragma("unroll")                                                               \
        for (int r = 0; r < 4; ++r) {                                                   \
            float gi = fsig(g[0][r]);                                                   \
            float gf = fsig(g[1][r]);                                                   \
            float gg = ftanh(g[2][r]);                                                  \
            float go = fsig(g[3][r]);                                                   \
            float c  = gf * creg[r] + gi * gg;                                          \
            creg[r] = c;                                                                \
            float h = go * ftanh(c);                                                    \
            hlast[r] = h;                                                               \
            shn[(q * 4 + r) * SH_STR + 16 * w + m] = f2bf(h);                           \
        }                                                                               \
        barrier_lgkm();                                                                 \
        {   /* fused value head for this step (reads shn; off critical path) */         \
            uint2 hv = *(const uint2*)&shn[vr * SH_STR + vp * 4];                       \
            float pv = bflo(hv.x) * wv.x + bfhi(hv.x) * wv.y                            \
                     + bflo(hv.y) * wv.z + bfhi(hv.y) * wv.w;                           \
            pv += __shfl_xor(pv, 1, 16);                                                \
            pv += __shfl_xor(pv, 2, 16);                                                \
            pv += __shfl_xor(pv, 4, 16);                                                \
            pv += __shfl_xor(pv, 8, 16);                                                \
            if (vp == 0) out[(size_t)(b0 + vr) * SS + rc0 + sl_] = pv + bvv;            \
        }                                                                               \
    } while (0)

    for (int sl = 0; sl < csr; sl += 2) {
        REC_STEP(0, sl);
        REC_STEP(1, sl + 1);
    }
    #undef REC_STEP

    if (!last) {
        const int jcol = 16 * w + m;
        #pragma unroll
        for (int r = 0; r < 4; ++r)
            hws[(size_t)bg * 1024 + (q * 4 + r) * 64 + jcol] = f2bf(hlast[r]);
        float4 cv; cv.x = creg[0]; cv.y = creg[1]; cv.z = creg[2]; cv.w = creg[3];
        *(float4*)(cws + ((size_t)bg * 256 + t) * 4) = cv;
    } else {
        const int jcol = 16 * w + m;
        #pragma unroll
        for (int r = 0; r < 4; ++r) {
            int row = b0 + q * 4 + r;
            out[BB * SS + (size_t)row * 64 + jcol]           = hlast[r];
            out[BB * SS + BB * 64 + (size_t)row * 64 + jcol] = creg[r];
        }
    }
}

// ============================================================================
// Combined pipeline dispatch: [0,nrec) rec(c)+fused-val | rest enc(c+1).
// No intra-dispatch dependencies (wx double-buffered).
// ============================================================================
__global__ __launch_bounds__(NT, 4)
void podcritic_step(const float* __restrict__ self_obs, const float* __restrict__ tm_obs,
                    const float* __restrict__ en_obs,   const float* __restrict__ cp_obs,
                    const float* __restrict__ b1, const float* __restrict__ b2,
                    const float* __restrict__ bih, const float* __restrict__ bhh,
                    const short8* __restrict__ img,
                    uint_t* __restrict__ wx_enc, const uint_t* __restrict__ wx_rec,
                    ushort_t* __restrict__ hws, float* __restrict__ cws,
                    const float* __restrict__ Wv, const float* __restrict__ bv,
                    float* __restrict__ out,
                    int enc_c0, int rec_c0, int nrec, int first, int last, int csr)
{
    __shared__ __align__(16) ushort_t smem[ENC_LDS_USHORTS];
    const int bid = blockIdx.x;
    if (bid < nrec) {
        rec_block(smem, img + 160 * 64, wx_rec, hws, cws, Wv, bv, out,
                  rec_c0, first, last, csr);
    } else {
        enc_block(smem, self_obs, tm_obs, en_obs, cp_obs, b1, b2, bih, bhh,
                  img, wx_enc, enc_c0, bid - nrec);
    }
}

// ============================================================================
// Fallback: fused kernel (only if ws too small) — round-2 structure.
// ============================================================================
__global__ __launch_bounds__(NT, 1)
void podcritic_mfma(const float* __restrict__ self_obs,
                    const float* __restrict__ tm_obs,
                    const float* __restrict__ en_obs,
                    const float* __restrict__ cp_obs,
                    const float* __restrict__ W1, const float* __restrict__ b1,
                    const float* __restrict__ W2, const float* __restrict__ b2,
                    const float* __restrict__ Wih, const float* __restrict__ bih,
                    const float* __restrict__ Whh, const float* __restrict__ bhh,
                    const float* __restrict__ Wv, const float* __restrict__ bv,
                    float* __restrict__ out)
{
    __shared__ __align__(16) ushort_t sx[2][NB * SX_STR];
    __shared__ __align__(16) ushort_t sh1[NB * SH1_STR];
    __shared__ __align__(16) ushort_t semb[NB * SEMB_STR];
    __shared__ __align__(16) ushort_t sh[NB * SH_STR];
    __shared__ float sWv[64];

    const int t  = threadIdx.x;
    const int w  = t >> 6;
    const int l  = t & 63;
    const int q  = l >> 4;
    const int m  = l & 15;
    const int b0 = blockIdx.x * NB;

    short8 w1f[4][2];
    short8 w2f[2][8];
    short8 wihf[4][4];
    short8 whhf[4][2];
    float bias1[4], bias2[2], bg[4];

    #pragma unroll
    for (int i = 0; i < 4; ++i) {
        int n = w * 64 + i * 16 + m;
        bias1[i] = b1[n];
        #pragma unroll
        for (int kk = 0; kk < 2; ++kk) {
            FragU u;
            #pragma unroll
            for (int j = 0; j < 8; ++j) {
                int k = kk * 32 + q * 8 + j;
                u.u[j] = f2bf(k < 47 ? W1[k * 256 + n] : 0.f);
            }
            w1f[i][kk] = u.v;
        }
    }
    #pragma unroll
    for (int i = 0; i < 2; ++i) {
        int n = 32 * w + i * 16 + m;
        bias2[i] = b2[n];
        #pragma unroll
        for (int kk = 0; kk < 8; ++kk) {
            FragU u;
            #pragma unroll
            for (int j = 0; j < 8; ++j) {
                int k = kk * 32 + q * 8 + j;
                u.u[j] = f2bf(W2[k * 128 + n]);
            }
            w2f[i][kk] = u.v;
        }
    }
    #pragma unroll
    for (int i = 0; i < 4; ++i) {
        int n = (w + 4 * i) * 16 + m;
        bg[i] = bih[n] + bhh[n];
        #pragma unroll
        for (int kk = 0; kk < 4; ++kk) {
            FragU u;
            #pragma unroll
            for (int j = 0; j < 8; ++j) {
                int k = kk * 32 + q * 8 + j;
                u.u[j] = f2bf(Wih[k * 256 + n]);
            }
            wihf[i][kk] = u.v;
        }
        #pragma unroll
        for (int kk = 0; kk < 2; ++kk) {
            FragU u;
            #pragma unroll
            for (int j = 0; j < 8; ++j) {
                int k = kk * 32 + q * 8 + j;
                u.u[j] = f2bf(Whh[k * 256 + n]);
            }
            whhf[i][kk] = u.v;
        }
    }
    const float bvv = bv[0];
    if (t < 64) sWv[t] = Wv[t];

    for (int idx = t; idx < NB * SH_STR; idx += NT) sh[idx] = 0;

    const int pcol = t & 63;
    const int prow = t >> 6;
    #pragma unroll
    for (int j = 0; j < 4; ++j) {
        int r  = 4 * j + prow;
        int bs = (b0 + r) * SS + 0;
        float v = 0.f;
        if (pcol < 15)      v = self_obs[bs * 15 + pcol];
        else if (pcol < 28) v = tm_obs[bs * 13 + (pcol - 15)];
        else if (pcol < 41) { int kk = pcol - 28;
                              v = 0.5f * (en_obs[(bs * 2) * 13 + kk] + en_obs[(bs * 2) * 13 + 13 + kk]); }
        else if (pcol < 47) v = cp_obs[bs * 6 + (pcol - 41)];
        sx[0][r * SX_STR + pcol] = f2bf(v);
    }
    __syncthreads();

    float creg[4] = {0.f, 0.f, 0.f, 0.f};
    float hreg[4] = {0.f, 0.f, 0.f, 0.f};
    int cur = 0;

    for (int s = 0; s < SS; ++s) {
        float pf[4];
        #pragma unroll
        for (int j = 0; j < 4; ++j) {
            float v = 0.f;
            if (s + 1 < SS) {
                int r  = 4 * j + prow;
                int bs = (b0 + r) * SS + (s + 1);
                if (pcol < 15)      v = self_obs[bs * 15 + pcol];
                else if (pcol < 28) v = tm_obs[bs * 13 + (pcol - 15)];
                else if (pcol < 41) { int kk = pcol - 28;
                                      v = 0.5f * (en_obs[(bs * 2) * 13 + kk] + en_obs[(bs * 2) * 13 + 13 + kk]); }
                else if (pcol < 47) v = cp_obs[bs * 6 + (pcol - 41)];
            }
            pf[j] = v;
        }

        {
            f32x4 c1[4] = {{0,0,0,0},{0,0,0,0},{0,0,0,0},{0,0,0,0}};
            #pragma unroll
            for (int kk = 0; kk < 2; ++kk) {
                short8 a = *(const short8*)&sx[cur][m * SX_STR + kk * 32 + q * 8];
                #pragma unroll
                for (int i = 0; i < 4; ++i)
                    c1[i] = __builtin_amdgcn_mfma_f32_16x16x32_bf16(a, w1f[i][kk], c1[i], 0, 0, 0);
            }
            #pragma unroll
            for (int i = 0; i < 4; ++i) {
                int col = w * 64 + i * 16 + m;
                #pragma unroll
                for (int r = 0; r < 4; ++r)
                    sh1[(q * 4 + r) * SH1_STR + col] = f2bf(fmaxf(c1[i][r] + bias1[i], 0.f));
            }
        }
        __syncthreads();

        {
            f32x4 c2[2] = {{0,0,0,0},{0,0,0,0}};
            #pragma unroll
            for (int kk = 0; kk < 8; ++kk) {
                short8 a = *(const short8*)&sh1[m * SH1_STR + kk * 32 + q * 8];
                #pragma unroll
                for (int i = 0; i < 2; ++i)
                    c2[i] = __builtin_amdgcn_mfma_f32_16x16x32_bf16(a, w2f[i][kk], c2[i], 0, 0, 0);
            }
            #pragma unroll
            for (int i = 0; i < 2; ++i) {
                int col = 32 * w + i * 16 + m;
                #pragma unroll
                for (int r = 0; r < 4; ++r)
                    semb[(q * 4 + r) * SEMB_STR + col] = f2bf(fmaxf(c2[i][r] + bias2[i], 0.f));
            }
        }
        __syncthreads();

        {
            f32x4 g[4];
            #pragma unroll
            for (int i = 0; i < 4; ++i) g[i] = (f32x4){bg[i], bg[i], bg[i], bg[i]};
            #pragma unroll
            for (int kk = 0; kk < 4; ++kk) {
                short8 a = *(const short8*)&semb[m * SEMB_STR + kk * 32 + q * 8];
                #pragma unroll
                for (int i = 0; i < 4; ++i)
                    g[i] = __builtin_amdgcn_mfma_f32_16x16x32_bf16(a, wihf[i][kk], g[i], 0, 0, 0);
            }
            #pragma unroll
            for (int kk = 0; kk < 2; ++kk) {
                short8 a = *(const short8*)&sh[m * SH_STR + kk * 32 + q * 8];
                #pragma unroll
                for (int i = 0; i < 4; ++i)
                    g[i] = __builtin_amdgcn_mfma_f32_16x16x32_bf16(a, whhf[i][kk], g[i], 0, 0, 0);
            }
            const int jcol = 16 * w + m;
            #pragma unroll
            for (int r = 0; r < 4; ++r) {
                float gi = fsig(g[0][r]);
                float gf = fsig(g[1][r]);
                float gg = ftanh(g[2][r]);
                float go = fsig(g[3][r]);
                float c  = gf * creg[r] + gi * gg;
                creg[r] = c;
                float h = go * ftanh(c);
                hreg[r] = h;
                sh[(q * 4 + r) * SH_STR + jcol] = f2bf(h);
            }
            #pragma unroll
            for (int j = 0; j < 4; ++j) {
                int r = 4 * j + prow;
                sx[cur ^ 1][r * SX_STR + pcol] = f2bf(pf[j]);
            }
        }
        __syncthreads();

        {
            int r = t >> 4, pp = t & 15;
            const ushort_t* hp = &sh[r * SH_STR + pp * 4];
            float pv = 0.f;
            #pragma unroll
            for (int j = 0; j < 4; ++j) pv += bf2f(hp[j]) * sWv[pp * 4 + j];
            pv += __shfl_xor(pv, 1, 16);
            pv += __shfl_xor(pv, 2, 16);
            pv += __shfl_xor(pv, 4, 16);
            pv += __shfl_xor(pv, 8, 16);
            if (pp == 0) out[(b0 + r) * SS + s] = pv + bvv;
        }
        cur ^= 1;
    }

    {
        const int jcol = 16 * w + m;
        #pragma unroll
        for (int r = 0; r < 4; ++r) {
            int row = b0 + q * 4 + r;
            out[BB * SS + row * 64 + jcol]           = hreg[r];
            out[BB * SS + BB * 64 + row * 64 + jcol] = creg[r];
        }
    }
}

extern "C" void kernel_launch(void* const* d_in, const int* in_sizes, int n_in,
                              void* d_out, int out_size, void* d_ws, size_t ws_size,
                              hipStream_t stream) {
    const float* self_obs = (const float*)d_in[0];
    const float* tm_obs   = (const float*)d_in[1];
    const float* en_obs   = (const float*)d_in[2];
    const float* cp_obs   = (const float*)d_in[3];
    const float* W1  = (const float*)d_in[4];
    const float* b1  = (const float*)d_in[5];
    const float* W2  = (const float*)d_in[6];
    const float* b2  = (const float*)d_in[7];
    const float* Wih = (const float*)d_in[8];
    const float* bih = (const float*)d_in[9];
    const float* Whh = (const float*)d_in[10];
    const float* bhh = (const float*)d_in[11];
    const float* Wv  = (const float*)d_in[12];
    const float* bv  = (const float*)d_in[13];
    float* out = (float*)d_out;

    const size_t h_bytes   = 256 * 1024 * 2;                // 524,288
    const size_t c_bytes   = 256 * 1024 * 4;                // 1,048,576
    const size_t img_bytes = 192 * 64 * 16;                 // 196,608

    auto need_for = [&](int cs) -> size_t {
        size_t wx_chunk = (size_t)cs * 256 * 2048 * 4;
        return 2 * wx_chunk + h_bytes + c_bytes + img_bytes;
    };

    int CSr = 0, NCHr = 0;
    if (ws_size >= need_for(32))      { CSr = 32; NCHr = 4; }   // ~136 MB
    else if (ws_size >= need_for(16)) { CSr = 16; NCHr = 8; }   // ~68.9 MB

    if (CSr) {
        const size_t wx_chunk = (size_t)CSr * 256 * 2048 * 4;
        char* p = (char*)d_ws;
        uint_t*   wxb[2] = { (uint_t*)p, (uint_t*)(p + wx_chunk) };
        ushort_t* hws    = (ushort_t*)(p + 2 * wx_chunk);
        float*    cws    = (float*)(p + 2 * wx_chunk + h_bytes);
        short8*   img    = (short8*)(p + 2 * wx_chunk + h_bytes + c_bytes);

        const int nenc_full = 128 * CSr;        // enc blocks per chunk

        podcritic_prep<<<48, NT, 0, stream>>>(W1, W2, Wih, Whh, img);

        // head: enc chunk 0 alone
        podcritic_step<<<nenc_full, NT, 0, stream>>>(
            self_obs, tm_obs, en_obs, cp_obs, b1, b2, bih, bhh, img,
            wxb[0], wxb[0], hws, cws, Wv, bv, out,
            /*enc_c0=*/0, /*rec_c0=*/0, /*nrec=*/0, 0, 0, CSr);

        for (int c = 0; c < NCHr; ++c) {
            int nenc = (c + 1 < NCHr) ? nenc_full : 0;
            int grid = 256 + nenc;
            podcritic_step<<<grid, NT, 0, stream>>>(
                self_obs, tm_obs, en_obs, cp_obs, b1, b2, bih, bhh, img,
                wxb[(c + 1) & 1], wxb[c & 1], hws, cws, Wv, bv, out,
                /*enc_c0=*/(c + 1) * CSr, /*rec_c0=*/c * CSr,
                /*nrec=*/256, (c == 0) ? 1 : 0, (c == NCHr - 1) ? 1 : 0, CSr);
        }
    } else {
        podcritic_mfma<<<BB / NB, NT, 0, stream>>>(
            self_obs, tm_obs, en_obs, cp_obs,
            W1, b1, W2, b2, Wih, bih, Whh, bhh, Wv, bv, out);
    }
}